// Round 5
// baseline (270.152 us; speedup 1.0000x reference)
//
#include <hip/hip_runtime.h>
#include <hip/hip_bf16.h>
#include <cstdint>

#define CIN 128
#define NH 8
#define CH 32
#define LDQ16 1024   // qkvg row stride in shorts: [q 256|k 256|v 256|g 256]

typedef short bf16x8 __attribute__((ext_vector_type(8)));
typedef short bf16x4 __attribute__((ext_vector_type(4)));
typedef float f32x4 __attribute__((ext_vector_type(4)));

__device__ __forceinline__ short f2bf(float f) {
  union { float f; unsigned u; } v; v.f = f;
  unsigned r = (v.u + 0x7FFFu + ((v.u >> 16) & 1u)) >> 16;   // RNE
  return (short)r;
}
__device__ __forceinline__ float bf2f(short s) {
  union { unsigned u; float f; } v; v.u = ((unsigned)(unsigned short)s) << 16;
  return v.f;
}
__device__ __forceinline__ unsigned pk2bf(float a, float b) {
  union { __hip_bfloat162 h; unsigned u; } cv;
  cv.h = __float22bfloat162_rn(make_float2(a, b));
  return cv.u;
}

// ---------------- merged prep: x->bf16 | weights->bf16 [n][k] | bias*log2e | mask detect ----
// blocks 0..4095: xb ; 4096..4159: WT/WoT ; 4160..4671: biasX ; 4672: detect_mask
__global__ __launch_bounds__(256) void prep(
    const float* __restrict__ x,
    const float* __restrict__ Wq, const float* __restrict__ Wk,
    const float* __restrict__ Wv, const float* __restrict__ Wg,
    const float* __restrict__ Wo, const float* __restrict__ bias,
    const uint4* __restrict__ mask,
    short* __restrict__ xb, short* __restrict__ WT, short* __restrict__ WoT,
    float* __restrict__ biasX, unsigned int* __restrict__ flag)
{
  __shared__ int viol;
  const int b = blockIdx.x;
  if (b < 4096) {
    int base = (b * 256 + threadIdx.x) * 8;
    float4 a = *(const float4*)(x + base);
    float4 c = *(const float4*)(x + base + 4);
    bf16x8 r;
    r[0] = f2bf(a.x); r[1] = f2bf(a.y); r[2] = f2bf(a.z); r[3] = f2bf(a.w);
    r[4] = f2bf(c.x); r[5] = f2bf(c.y); r[6] = f2bf(c.z); r[7] = f2bf(c.w);
    *(bf16x8*)(xb + base) = r;
  } else if (b < 4160) {
    // Wq folded scale: log2(e)/sqrt(32)  -> scores come out pre-multiplied by log2e
    const float qscale = 0.25504430213978686f;
    int bb = b - 4096;
#pragma unroll
    for (int e = 0; e < 10; ++e) {
      int o = bb * 2560 + e * 256 + threadIdx.x;
      if (o < 131072) {
        int n = o >> 7, k = o & 127;
        int seg = n >> 8, nn = n & 255;
        const float* W = (seg == 0) ? Wq : (seg == 1) ? Wk : (seg == 2) ? Wv : Wg;
        float v = W[k * 256 + nn];
        if (seg == 0) v *= qscale;
        WT[o] = f2bf(v);
      } else {
        int o2 = o - 131072;
        int n = o2 >> 8, k = o2 & 255;
        WoT[o2] = f2bf(Wo[k * 128 + n]);
      }
    }
  } else if (b < 4672) {
    const float LOG2E = 1.4426950408889634f;
    int idx = ((b - 4160) * 256 + threadIdx.x) * 4;
    float4 v = *(const float4*)(bias + idx);
    v.x *= LOG2E; v.y *= LOG2E; v.z *= LOG2E; v.w *= LOG2E;
    *(float4*)(biasX + idx) = v;
  } else {
    if (threadIdx.x == 0) viol = 0;
    __syncthreads();
    int v = 0;
#pragma unroll
    for (int j = 0; j < 16; ++j) {
      uint4 w = mask[j * 256 + threadIdx.x];
      v |= (w.x > 1u) | (w.y > 1u) | (w.z > 1u) | (w.w > 1u);
    }
    if (v) atomicOr(&viol, 1);
    __syncthreads();
    if (threadIdx.x == 0) *flag = viol ? 0u : 1u;
  }
}

// ---------------- QKVG projection, bf16 MFMA ----------------
__global__ __launch_bounds__(256) void proj_qkvg(
    const short* __restrict__ xb, const short* __restrict__ WT,
    const float* __restrict__ bg, short* __restrict__ qkvg)
{
  __shared__ short Al[64 * 136];
  __shared__ short Bl[128 * 136];
  const int tid = threadIdx.x;
  const int lane = tid & 63, w = tid >> 6;
  const int g = lane >> 4, c16 = lane & 15;
  const int wr = w & 1, wc = w >> 1;
  const int n0 = blockIdx.x * 128;
  const int row0 = blockIdx.y * 64;

  {
    const short* src = xb + (size_t)row0 * 128;
#pragma unroll
    for (int ch = 0; ch < 4; ++ch) {
      int c = ch * 256 + tid;
      int r = c >> 4, kc = c & 15;
      *(bf16x8*)&Al[r * 136 + kc * 8] = *(const bf16x8*)(src + r * 128 + kc * 8);
    }
    const short* wsrc = WT + (size_t)n0 * 128;
#pragma unroll
    for (int ch = 0; ch < 8; ++ch) {
      int c = ch * 256 + tid;
      int r = c >> 4, kc = c & 15;
      *(bf16x8*)&Bl[r * 136 + kc * 8] = *(const bf16x8*)(wsrc + r * 128 + kc * 8);
    }
  }
  __syncthreads();

  f32x4 acc[2][4];
#pragma unroll
  for (int rt = 0; rt < 2; ++rt)
#pragma unroll
    for (int ct = 0; ct < 4; ++ct) acc[rt][ct] = (f32x4){0.f, 0.f, 0.f, 0.f};

#pragma unroll
  for (int kk = 0; kk < 4; ++kk) {
    bf16x8 af[2], bfr[4];
#pragma unroll
    for (int rt = 0; rt < 2; ++rt)
      af[rt] = *(const bf16x8*)&Al[(wr * 32 + rt * 16 + c16) * 136 + kk * 32 + g * 8];
#pragma unroll
    for (int ct = 0; ct < 4; ++ct)
      bfr[ct] = *(const bf16x8*)&Bl[(wc * 64 + ct * 16 + c16) * 136 + kk * 32 + g * 8];
#pragma unroll
    for (int rt = 0; rt < 2; ++rt)
#pragma unroll
      for (int ct = 0; ct < 4; ++ct)
        acc[rt][ct] = __builtin_amdgcn_mfma_f32_16x16x32_bf16(af[rt], bfr[ct], acc[rt][ct], 0, 0, 0);
  }

  const int seg3 = (n0 >= 768);
  float bgv[4];
  if (seg3) {
#pragma unroll
    for (int ct = 0; ct < 4; ++ct)
      bgv[ct] = bg[n0 - 768 + wc * 64 + ct * 16 + c16];
  }
#pragma unroll
  for (int rt = 0; rt < 2; ++rt)
#pragma unroll
    for (int ct = 0; ct < 4; ++ct) {
      int col = n0 + wc * 64 + ct * 16 + c16;
#pragma unroll
      for (int i = 0; i < 4; ++i) {
        int row = row0 + wr * 32 + rt * 16 + g * 4 + i;
        float v = acc[rt][ct][i];
        if (seg3) v = 1.f / (1.f + __expf(-(v + bgv[ct])));
        qkvg[(size_t)row * LDQ16 + col] = f2bf(v);
      }
    }
}

// ---------------- MFMA flash attention, S^T formulation, single-pass ----------------
// R1-proven structure (256 thr / 4 waves, K+V in LDS, (256,4), 4 blocks/CU) +
// Round-5 delta: explicit 1-step software pipeline over the 16 (ch,kt) steps.
// LOADSTEP(s+1) issues {kf b128, v 2xb64, bias 4x dwordx4} a full step ahead of
// COMPUTE(s); manual x2 unroll makes the A/B ping-pong pure static renaming.
// Mask nibble per step comes from a per-thread packed 64-bit (no runtime-indexed
// arrays -> no scratch). exp2 path; mask folded into clamp limit.
// LDS shorts: kL@0 [256][40]; vTd@10240 [32][132]dw; lL@18688 (256 f32); mask@19200.
__global__ __launch_bounds__(256, 4) void attn(
    short* __restrict__ qkvg, const float* __restrict__ bias,
    const void* __restrict__ maskraw, const unsigned int* __restrict__ flagp)
{
  __shared__ __align__(16) short lds16[19216];
  const int tid = threadIdx.x;
  const int h = blockIdx.x;
  const int srow = blockIdx.y;
  const int lane = tid & 63, w = tid >> 6;
  const int g = lane >> 4, c16 = lane & 15;
  short* rowbase = qkvg + (size_t)srow * (256 * LDQ16);
  unsigned int* vTd = (unsigned int*)&lds16[10240];
  float* lL = (float*)&lds16[18688];
  unsigned int* scratch = (unsigned int*)&lds16[19200];

  // ---- mask row -> 8x u32 bits ----
  const unsigned int fl = *flagp;
  int mv = fl ? ((const int*)maskraw)[srow * 256 + tid]
              : (int)((const unsigned char*)maskraw)[srow * 256 + tid];
  unsigned long long bb = __ballot(mv != 0);
  if (lane == 0) {
    scratch[w * 2 + 0] = (unsigned int)bb;
    scratch[w * 2 + 1] = (unsigned int)(bb >> 32);
  }

  // ---- stage k -> kL[key][40-pad] (b128), v -> vTd packed key-pairs (b32) ----
#pragma unroll
  for (int it = 0; it < 2; ++it) {
    int c = it * 256 + tid;          // keypair(128) x cquad(4)
    int kp = c >> 2, cv = c & 3;
    const short* p0 = rowbase + (size_t)(2 * kp) * LDQ16 + 256 + h * CH + cv * 8;
    bf16x8 k0 = *(const bf16x8*)p0;
    bf16x8 k1 = *(const bf16x8*)(p0 + LDQ16);
    bf16x8 v0 = *(const bf16x8*)(p0 + 256);
    bf16x8 v1 = *(const bf16x8*)(p0 + LDQ16 + 256);
    *(bf16x8*)&lds16[(2 * kp) * 40 + cv * 8] = k0;
    *(bf16x8*)&lds16[(2 * kp + 1) * 40 + cv * 8] = k1;
#pragma unroll
    for (int j = 0; j < 8; ++j)
      vTd[(cv * 8 + j) * 132 + kp] =
          ((unsigned)(unsigned short)v0[j]) | (((unsigned)(unsigned short)v1[j]) << 16);
  }

  // ---- q B-frags direct from global bf16 (B[k=chan][n=q] wants [q][chan] layout) ----
  const int qb = w * 64;
  bf16x8 qf[4];
#pragma unroll
  for (int qt = 0; qt < 4; ++qt)
    qf[qt] = *(const bf16x8*)(rowbase + (size_t)(qb + qt * 16 + c16) * LDQ16 + h * CH + g * 8);

  __syncthreads();   // only barrier: staging + mask visible

  // ---- per-thread packed mask: nibble for step s at bits [4s..4s+3] ----
  unsigned long long Mmask = 0ull;
#pragma unroll
  for (int j = 0; j < 8; ++j) {
    unsigned wj = scratch[j];
    unsigned lo = (wj >> (g * 4)) & 0xFu;
    unsigned hi = (wj >> (16 + g * 4)) & 0xFu;
    Mmask |= (unsigned long long)(lo | (hi << 4)) << (8 * j);
  }

  float l_[4] = {0.f, 0.f, 0.f, 0.f};
  const f32x4 zero4 = {0.f, 0.f, 0.f, 0.f};
  f32x4 O[4][2];
#pragma unroll
  for (int qt = 0; qt < 4; ++qt) { O[qt][0] = zero4; O[qt][1] = zero4; }

  const float* bh = bias + (size_t)h * 65536;
  const float LIM = 122.f;
  const float NEG = -3.0e38f;

  // per-thread base pointers; step s adds: kf s*640 shorts, v s*8 dwords, bias s*16 floats
  const short* kfb = &lds16[c16 * 40 + g * 8];
  const unsigned* vlb = &vTd[(size_t)c16 * 132 + g * 2];
  const unsigned* vhb = &vTd[(size_t)(16 + c16) * 132 + g * 2];
  const float* bb0 = bh + (size_t)(qb + 0 * 16 + c16) * 256 + g * 4;
  const float* bb1 = bh + (size_t)(qb + 1 * 16 + c16) * 256 + g * 4;
  const float* bb2 = bh + (size_t)(qb + 2 * 16 + c16) * 256 + g * 4;
  const float* bb3 = bh + (size_t)(qb + 3 * 16 + c16) * 256 + g * 4;

#define LOADSTEP(S, KF, VLO, VHI, BB) {                                   \
    KF = *(const bf16x8*)(kfb + (S) * 640);                               \
    union { unsigned u[2]; bf16x4 v; } t0_, t1_;                          \
    const unsigned* pl_ = vlb + (S) * 8;                                  \
    const unsigned* ph_ = vhb + (S) * 8;                                  \
    t0_.u[0] = pl_[0]; t0_.u[1] = pl_[1];                                 \
    t1_.u[0] = ph_[0]; t1_.u[1] = ph_[1];                                 \
    VLO = t0_.v; VHI = t1_.v;                                             \
    BB[0] = *(const f32x4*)(bb0 + (S) * 16);                              \
    BB[1] = *(const f32x4*)(bb1 + (S) * 16);                              \
    BB[2] = *(const f32x4*)(bb2 + (S) * 16);                              \
    BB[3] = *(const f32x4*)(bb3 + (S) * 16);                              \
  }

#define QTBODY(QT, KF, VLO, VHI, BB) {                                    \
    f32x4 Sv = __builtin_amdgcn_mfma_f32_16x16x32_bf16(KF, qf[QT], zero4, 0, 0, 0); \
    float p0 = __builtin_exp2f(fminf(Sv[0] + BB[QT][0], ml0));            \
    float p1 = __builtin_exp2f(fminf(Sv[1] + BB[QT][1], ml1));            \
    float p2 = __builtin_exp2f(fminf(Sv[2] + BB[QT][2], ml2));            \
    float p3 = __builtin_exp2f(fminf(Sv[3] + BB[QT][3], ml3));            \
    l_[QT] += (p0 + p1) + (p2 + p3);                                      \
    union { unsigned u[2]; bf16x4 v; } pu_;                               \
    pu_.u[0] = pk2bf(p0, p1);                                             \
    pu_.u[1] = pk2bf(p2, p3);                                             \
    O[QT][0] = __builtin_amdgcn_mfma_f32_16x16x16bf16_1k(pu_.v, VLO, O[QT][0], 0, 0, 0); \
    O[QT][1] = __builtin_amdgcn_mfma_f32_16x16x16bf16_1k(pu_.v, VHI, O[QT][1], 0, 0, 0); \
  }

#define COMPUTE(S, KF, VLO, VHI, BB) {                                    \
    unsigned nib = (unsigned)(Mmask >> ((S) * 4)) & 0xFu;                 \
    const float ml0 = (nib & 1u) ? LIM : NEG;                             \
    const float ml1 = (nib & 2u) ? LIM : NEG;                             \
    const float ml2 = (nib & 4u) ? LIM : NEG;                             \
    const float ml3 = (nib & 8u) ? LIM : NEG;                             \
    QTBODY(0, KF, VLO, VHI, BB)                                           \
    QTBODY(1, KF, VLO, VHI, BB)                                           \
    QTBODY(2, KF, VLO, VHI, BB)                                           \
    QTBODY(3, KF, VLO, VHI, BB)                                           \
  }

  bf16x8 kfA, kfB;
  bf16x4 vloA, vhiA, vloB, vhiB;
  f32x4 bbA[4], bbB[4];

  LOADSTEP(0, kfA, vloA, vhiA, bbA);
#pragma unroll 1
  for (int s = 0; s < 16; s += 2) {
    LOADSTEP(s + 1, kfB, vloB, vhiB, bbB);
    COMPUTE(s, kfA, vloA, vhiA, bbA);
    LOADSTEP((s + 2) & 15, kfA, vloA, vhiA, bbA);
    COMPUTE(s + 1, kfB, vloB, vhiB, bbB);
  }
#undef LOADSTEP
#undef QTBODY
#undef COMPUTE

  // ---- l reduction: sum over 4 g-groups; park per-wave in lL ----
#pragma unroll
  for (int qt = 0; qt < 4; ++qt) {
    float v = l_[qt];
    v += __shfl_xor(v, 16);
    v += __shfl_xor(v, 32);
    if (lane < 16) lL[w * 64 + qt * 16 + c16] = v;
  }

  // ---- epilogue: O/l * gate -> q slot (bf16) ----
#pragma unroll
  for (int qt = 0; qt < 4; ++qt)
#pragma unroll
    for (int i = 0; i < 4; ++i) {
      float l = lL[w * 64 + qt * 16 + g * 4 + i];
      float inv = 1.f / l;
      short* orow = rowbase + (size_t)(qb + qt * 16 + g * 4 + i) * LDQ16;
#pragma unroll
      for (int half = 0; half < 2; ++half) {
        int c = half * 16 + c16;
        float gv = bf2f(orow[768 + h * CH + c]);
        orow[h * CH + c] = f2bf(O[qt][half][i] * inv * gv);
      }
    }
}

// ---------------- output projection: out = oG @ Wo + bo, bf16 MFMA ----------------
__global__ __launch_bounds__(256) void out_proj(
    const short* __restrict__ og, const short* __restrict__ WoT,
    const float* __restrict__ bo, float* __restrict__ out)
{
  __shared__ short Al[64 * 136];
  __shared__ short Bl[128 * 136];
  const int tid = threadIdx.x;
  const int lane = tid & 63, w = tid >> 6;
  const int g = lane >> 4, c16 = lane & 15;
  const int wr = w & 1, wc = w >> 1;
  const int row0 = blockIdx.x * 64;

  f32x4 acc[2][4];
#pragma unroll
  for (int rt = 0; rt < 2; ++rt)
#pragma unroll
    for (int ct = 0; ct < 4; ++ct) acc[rt][ct] = (f32x4){0.f, 0.f, 0.f, 0.f};

  for (int kk0 = 0; kk0 < 256; kk0 += 128) {
#pragma unroll
    for (int ch = 0; ch < 4; ++ch) {
      int c = ch * 256 + tid;
      int r = c >> 4, kc = c & 15;
      *(bf16x8*)&Al[r * 136 + kc * 8] =
          *(const bf16x8*)(og + (size_t)(row0 + r) * LDQ16 + kk0 + kc * 8);
    }
#pragma unroll
    for (int ch = 0; ch < 8; ++ch) {
      int c = ch * 256 + tid;
      int r = c >> 4, kc = c & 15;
      *(bf16x8*)&Bl[r * 136 + kc * 8] =
          *(const bf16x8*)(WoT + (size_t)r * 256 + kk0 + kc * 8);
    }
    __syncthreads();
#pragma unroll
    for (int kk = 0; kk < 4; ++kk) {
      bf16x8 af[2], bfr[4];
#pragma unroll
      for (int rt = 0; rt < 2; ++rt)
        af[rt] = *(const bf16x8*)&Al[(wr * 32 + rt * 16 + c16) * 136 + kk * 32 + g * 8];
#pragma unroll
      for (int ct = 0; ct < 4; ++ct)
        bfr[ct] = *(const bf16x8*)&Bl[(wc * 64 + ct * 16 + c16) * 136 + kk * 32 + g * 8];
#pragma unroll
      for (int rt = 0; rt < 2; ++rt)
#pragma unroll
        for (int ct = 0; ct < 4; ++ct)
          acc[rt][ct] = __builtin_amdgcn_mfma_f32_16x16x32_bf16(af[rt], bfr[ct], acc[rt][ct], 0, 0, 0);
    }
    __syncthreads();
  }

#pragma unroll
  for (int rt = 0; rt < 2; ++rt)
#pragma unroll
    for (int ct = 0; ct < 4; ++ct) {
      int col = wc * 64 + ct * 16 + c16;
      float bv = bo[col];
#pragma unroll
      for (int i = 0; i < 4; ++i) {
        int row = row0 + wr * 32 + rt * 16 + g * 4 + i;
        out[(size_t)row * CIN + col] = acc[rt][ct][i] + bv;
      }
    }
}

extern "C" void kernel_launch(void* const* d_in, const int* in_sizes, int n_in,
                              void* d_out, int out_size, void* d_ws, size_t ws_size,
                              hipStream_t stream) {
  const float* x    = (const float*)d_in[0];
  const float* bias = (const float*)d_in[1];
  const void*  mask = d_in[2];
  const float* Wq   = (const float*)d_in[3];
  const float* Wk   = (const float*)d_in[4];
  const float* Wv   = (const float*)d_in[5];
  const float* Wo   = (const float*)d_in[6];
  const float* bo   = (const float*)d_in[7];
  const float* Wg   = (const float*)d_in[8];
  const float* bg   = (const float*)d_in[9];
  float* out = (float*)d_out;

  // ws: [flag 256B][WT 256KB][WoT 64KB][xb 16MB][qkvg bf16 128MB][biasX 2MB]
  unsigned int* flag = (unsigned int*)d_ws;
  short* WT   = (short*)((char*)d_ws + 256);
  short* WoT  = WT + 131072;
  short* xb   = WoT + 32768;
  short* qkvg = xb + (size_t)65536 * 128;
  float* biasX = (float*)(qkvg + (size_t)65536 * 1024);

  prep<<<4673, 256, 0, stream>>>(x, Wq, Wk, Wv, Wg, Wo, bias, (const uint4*)mask,
                                 xb, WT, WoT, biasX, flag);
  proj_qkvg<<<dim3(8, 1024), 256, 0, stream>>>(xb, WT, bg, qkvg);
  attn<<<dim3(NH, 256), 256, 0, stream>>>(qkvg, biasX, mask, flag);
  out_proj<<<1024, 256, 0, stream>>>(qkvg, WoT, bo, out);
}

// Round 6
// 266.774 us; speedup vs baseline: 1.0127x; 1.0127x over previous
//
#include <hip/hip_runtime.h>
#include <hip/hip_bf16.h>
#include <cstdint>

#define CIN 128
#define NH 8
#define CH 32
#define LDQ16 1024   // qkvg row stride in shorts: [q 256|k 256|v 256|g 256]

typedef short bf16x8 __attribute__((ext_vector_type(8)));
typedef short bf16x4 __attribute__((ext_vector_type(4)));
typedef float f32x4 __attribute__((ext_vector_type(4)));

__device__ __forceinline__ short f2bf(float f) {
  union { float f; unsigned u; } v; v.f = f;
  unsigned r = (v.u + 0x7FFFu + ((v.u >> 16) & 1u)) >> 16;   // RNE
  return (short)r;
}
__device__ __forceinline__ float bf2f(short s) {
  union { unsigned u; float f; } v; v.u = ((unsigned)(unsigned short)s) << 16;
  return v.f;
}
__device__ __forceinline__ unsigned pk2bf(float a, float b) {
  union { __hip_bfloat162 h; unsigned u; } cv;
  cv.h = __float22bfloat162_rn(make_float2(a, b));
  return cv.u;
}

// ---------------- merged prep: x->bf16 | weights->bf16 [n][k] | mask detect ----------------
// blocks 0..4095: xb ; 4096..4159: WT/WoT ; 4160: detect_mask
__global__ __launch_bounds__(256) void prep(
    const float* __restrict__ x,
    const float* __restrict__ Wq, const float* __restrict__ Wk,
    const float* __restrict__ Wv, const float* __restrict__ Wg,
    const float* __restrict__ Wo,
    const uint4* __restrict__ mask,
    short* __restrict__ xb, short* __restrict__ WT, short* __restrict__ WoT,
    unsigned int* __restrict__ flag)
{
  __shared__ int viol;
  const int b = blockIdx.x;
  if (b < 4096) {
    int base = (b * 256 + threadIdx.x) * 8;
    float4 a = *(const float4*)(x + base);
    float4 c = *(const float4*)(x + base + 4);
    bf16x8 r;
    r[0] = f2bf(a.x); r[1] = f2bf(a.y); r[2] = f2bf(a.z); r[3] = f2bf(a.w);
    r[4] = f2bf(c.x); r[5] = f2bf(c.y); r[6] = f2bf(c.z); r[7] = f2bf(c.w);
    *(bf16x8*)(xb + base) = r;
  } else if (b < 4160) {
    const float qscale = 0.17677669529663689f;  // 1/sqrt(32)
    int bb = b - 4096;
#pragma unroll
    for (int e = 0; e < 10; ++e) {
      int o = bb * 2560 + e * 256 + threadIdx.x;
      if (o < 131072) {
        int n = o >> 7, k = o & 127;
        int seg = n >> 8, nn = n & 255;
        const float* W = (seg == 0) ? Wq : (seg == 1) ? Wk : (seg == 2) ? Wv : Wg;
        float v = W[k * 256 + nn];
        if (seg == 0) v *= qscale;
        WT[o] = f2bf(v);
      } else {
        int o2 = o - 131072;
        int n = o2 >> 8, k = o2 & 255;
        WoT[o2] = f2bf(Wo[k * 128 + n]);
      }
    }
  } else {
    if (threadIdx.x == 0) viol = 0;
    __syncthreads();
    int v = 0;
#pragma unroll
    for (int j = 0; j < 16; ++j) {
      uint4 w = mask[j * 256 + threadIdx.x];
      v |= (w.x > 1u) | (w.y > 1u) | (w.z > 1u) | (w.w > 1u);
    }
    if (v) atomicOr(&viol, 1);
    __syncthreads();
    if (threadIdx.x == 0) *flag = viol ? 0u : 1u;
  }
}

// ---------------- QKVG projection v2: 128x128 tile, full-K stage, transposed epilogue ----
// 4 waves in 2x2; wave tile 64x64; K=128 staged once (one barrier, 64 MFMA/wave).
// MFMA computes C^T (operand-swapped: A=W-frag, B=x-frag) so each lane holds 4
// consecutive OUTPUT COLUMNS -> pk2bf pairs -> ds_write_b64 into padded ldsT ->
// barrier -> b128 coalesced global stores (8x16B/thread vs 32x2B scattered).
// Sigmoid gate folded before the ldsT write for the g segment (n0>=768).
__global__ __launch_bounds__(256) void proj_qkvg(
    const short* __restrict__ xb, const short* __restrict__ WT,
    const float* __restrict__ bg, short* __restrict__ qkvg)
{
  __shared__ short Al[128 * 136];   // x rows   [m][k] pad136 ; reused as ldsT [m][n]
  __shared__ short Bl[128 * 136];   // W rows   [n][k] pad136
  const int tid = threadIdx.x;
  const int lane = tid & 63, w = tid >> 6;
  const int g = lane >> 4, c16 = lane & 15;
  const int wr = w & 1, wc = w >> 1;
  const int n0 = blockIdx.x * 128;
  const int row0 = blockIdx.y * 128;

  // ---- stage A and B (coalesced b128 loads, padded ds_writes) ----
  {
    const short* asrc = xb + (size_t)row0 * 128;
    const short* bsrc = WT + (size_t)n0 * 128;
#pragma unroll
    for (int ch = 0; ch < 8; ++ch) {
      int c = ch * 256 + tid;
      int r = c >> 4, kc = c & 15;
      *(bf16x8*)&Al[r * 136 + kc * 8] = *(const bf16x8*)(asrc + r * 128 + kc * 8);
      *(bf16x8*)&Bl[r * 136 + kc * 8] = *(const bf16x8*)(bsrc + r * 128 + kc * 8);
    }
  }
  __syncthreads();

  // ---- MFMA: acc[ct][rt] = C^T, value = out[row0+wr*64+rt*16+c16][n0+wc*64+ct*16+g*4+i]
  f32x4 acc[4][4];
#pragma unroll
  for (int ct = 0; ct < 4; ++ct)
#pragma unroll
    for (int rt = 0; rt < 4; ++rt) acc[ct][rt] = (f32x4){0.f, 0.f, 0.f, 0.f};

#pragma unroll
  for (int kk = 0; kk < 4; ++kk) {
    bf16x8 af[4], bfr[4];
#pragma unroll
    for (int rt = 0; rt < 4; ++rt)
      af[rt] = *(const bf16x8*)&Al[(wr * 64 + rt * 16 + c16) * 136 + kk * 32 + g * 8];
#pragma unroll
    for (int ct = 0; ct < 4; ++ct)
      bfr[ct] = *(const bf16x8*)&Bl[(wc * 64 + ct * 16 + c16) * 136 + kk * 32 + g * 8];
#pragma unroll
    for (int ct = 0; ct < 4; ++ct)
#pragma unroll
      for (int rt = 0; rt < 4; ++rt)
        acc[ct][rt] = __builtin_amdgcn_mfma_f32_16x16x32_bf16(bfr[ct], af[rt], acc[ct][rt], 0, 0, 0);
  }
  __syncthreads();   // all staging reads done; reuse Al region as ldsT

  // ---- transpose via LDS: bf16 pack + b64 writes at [m][n] ----
  short* ldsT = Al;
  const int seg3 = (n0 >= 768);
#pragma unroll
  for (int ct = 0; ct < 4; ++ct) {
    float4 bgv = {0.f, 0.f, 0.f, 0.f};
    if (seg3) bgv = *(const float4*)(bg + (n0 - 768) + wc * 64 + ct * 16 + g * 4);
#pragma unroll
    for (int rt = 0; rt < 4; ++rt) {
      float v0 = acc[ct][rt][0], v1 = acc[ct][rt][1];
      float v2 = acc[ct][rt][2], v3 = acc[ct][rt][3];
      if (seg3) {
        v0 = 1.f / (1.f + __expf(-(v0 + bgv.x)));
        v1 = 1.f / (1.f + __expf(-(v1 + bgv.y)));
        v2 = 1.f / (1.f + __expf(-(v2 + bgv.z)));
        v3 = 1.f / (1.f + __expf(-(v3 + bgv.w)));
      }
      union { unsigned u[2]; bf16x4 v; } pu;
      pu.u[0] = pk2bf(v0, v1);
      pu.u[1] = pk2bf(v2, v3);
      *(bf16x4*)&ldsT[(wr * 64 + rt * 16 + c16) * 136 + wc * 64 + ct * 16 + g * 4] = pu.v;
    }
  }
  __syncthreads();

  // ---- coalesced store: rows of ldsT -> qkvg (b128) ----
  {
    short* dst = qkvg + (size_t)row0 * LDQ16 + n0;
#pragma unroll
    for (int ch = 0; ch < 8; ++ch) {
      int c = ch * 256 + tid;
      int r = c >> 4, kc = c & 15;
      bf16x8 vv = *(const bf16x8*)&ldsT[r * 136 + kc * 8];
      *(bf16x8*)(dst + (size_t)r * LDQ16 + kc * 8) = vv;
    }
  }
}

// ---------------- MFMA flash attention, S^T formulation, single-pass ----------------
// R1-proven: 256 thr / 4 waves, K+V in LDS, P in registers via 16x16x16 PV, (256,4).
// LDS shorts: kL@0 [256][40]; vTd@10240 [32][132]dw; lL@18688 (256 f32); mask@19200.
__global__ __launch_bounds__(256, 4) void attn(
    short* __restrict__ qkvg, const float* __restrict__ bias,
    const void* __restrict__ maskraw, const unsigned int* __restrict__ flagp)
{
  __shared__ __align__(16) short lds16[19216];
  const int tid = threadIdx.x;
  const int h = blockIdx.x;
  const int srow = blockIdx.y;
  const int lane = tid & 63, w = tid >> 6;
  const int g = lane >> 4, c16 = lane & 15;
  short* rowbase = qkvg + (size_t)srow * (256 * LDQ16);
  unsigned int* vTd = (unsigned int*)&lds16[10240];
  float* lL = (float*)&lds16[18688];
  unsigned int* scratch = (unsigned int*)&lds16[19200];

  // ---- mask row -> 8x u32 bits ----
  const unsigned int fl = *flagp;
  int mv = fl ? ((const int*)maskraw)[srow * 256 + tid]
              : (int)((const unsigned char*)maskraw)[srow * 256 + tid];
  unsigned long long bb = __ballot(mv != 0);
  if (lane == 0) {
    scratch[w * 2 + 0] = (unsigned int)bb;
    scratch[w * 2 + 1] = (unsigned int)(bb >> 32);
  }

  // ---- stage k -> kL[key][40-pad] (b128), v -> vTd packed key-pairs (b32) ----
#pragma unroll
  for (int it = 0; it < 2; ++it) {
    int c = it * 256 + tid;          // keypair(128) x cquad(4)
    int kp = c >> 2, cv = c & 3;
    const short* p0 = rowbase + (size_t)(2 * kp) * LDQ16 + 256 + h * CH + cv * 8;
    bf16x8 k0 = *(const bf16x8*)p0;
    bf16x8 k1 = *(const bf16x8*)(p0 + LDQ16);
    bf16x8 v0 = *(const bf16x8*)(p0 + 256);
    bf16x8 v1 = *(const bf16x8*)(p0 + LDQ16 + 256);
    *(bf16x8*)&lds16[(2 * kp) * 40 + cv * 8] = k0;
    *(bf16x8*)&lds16[(2 * kp + 1) * 40 + cv * 8] = k1;
#pragma unroll
    for (int j = 0; j < 8; ++j)
      vTd[(cv * 8 + j) * 132 + kp] =
          ((unsigned)(unsigned short)v0[j]) | (((unsigned)(unsigned short)v1[j]) << 16);
  }

  // ---- q B-frags direct from global bf16 (B[k=chan][n=q] wants [q][chan] layout) ----
  const int qb = w * 64;
  bf16x8 qf[4];
#pragma unroll
  for (int qt = 0; qt < 4; ++qt)
    qf[qt] = *(const bf16x8*)(rowbase + (size_t)(qb + qt * 16 + c16) * LDQ16 + h * CH + g * 8);

  __syncthreads();   // only barrier: staging + mask visible

  unsigned int mb[8];
#pragma unroll
  for (int j = 0; j < 8; ++j) mb[j] = scratch[j];

  const f32x4 zero4 = {0.f, 0.f, 0.f, 0.f};
  float l_[4] = {0.f, 0.f, 0.f, 0.f};
  f32x4 O[4][2];
#pragma unroll
  for (int qt = 0; qt < 4; ++qt) { O[qt][0] = zero4; O[qt][1] = zero4; }

  const float* bh = bias + (size_t)h * 65536;

  for (int ch = 0; ch < 8; ++ch) {
    // prefetch bias: thread covers keys ch*32+kt*16+g*4.. (4 consecutive) at q=qt*16+c16
    float4 bb4[2][4];
#pragma unroll
    for (int kt = 0; kt < 2; ++kt)
#pragma unroll
      for (int qt = 0; qt < 4; ++qt)
        bb4[kt][qt] = *(const float4*)(bh + (size_t)(qb + qt * 16 + c16) * 256 +
                                       ch * 32 + kt * 16 + g * 4);

#pragma unroll
    for (int kt = 0; kt < 2; ++kt) {
      // A-frag K: row=key ch*32+kt*16+c16, k-elems = chans g*8..+7
      bf16x8 kf = *(const bf16x8*)&lds16[(ch * 32 + kt * 16 + c16) * 40 + g * 8];
      // PV B-frags (16x16x16): B[k=key][n=chan]: lane holds keys g*4..+3 at chan c16 / 16+c16.
      bf16x4 vlo, vhi;
      {
        union { unsigned u[2]; bf16x4 v; } t0, t1;
        const unsigned* plo = &vTd[(size_t)c16 * 132 + ch * 16 + kt * 8 + g * 2];
        const unsigned* phi = &vTd[(size_t)(16 + c16) * 132 + ch * 16 + kt * 8 + g * 2];
        t0.u[0] = plo[0]; t0.u[1] = plo[1];
        t1.u[0] = phi[0]; t1.u[1] = phi[1];
        vlo = t0.v; vhi = t1.v;
      }
      const unsigned nib = (mb[ch] >> (kt * 16 + g * 4)) & 0xFu;
      float em[4];
#pragma unroll
      for (int i = 0; i < 4; ++i) em[i] = ((nib >> i) & 1u) ? 1.f : 0.f;
#pragma unroll
      for (int qt = 0; qt < 4; ++qt) {
        f32x4 S = __builtin_amdgcn_mfma_f32_16x16x32_bf16(kf, qf[qt], zero4, 0, 0, 0);
        float p0 = em[0] * __expf(fminf(S[0] + bb4[kt][qt].x, 85.f));
        float p1 = em[1] * __expf(fminf(S[1] + bb4[kt][qt].y, 85.f));
        float p2 = em[2] * __expf(fminf(S[2] + bb4[kt][qt].z, 85.f));
        float p3 = em[3] * __expf(fminf(S[3] + bb4[kt][qt].w, 85.f));
        l_[qt] += (p0 + p1) + (p2 + p3);
        // P A-frag for 16x16x16: lane(g,c16) holds P[q=c16][keys g*4..+3] -- exactly p0..p3.
        union { unsigned u[2]; bf16x4 v; } pu;
        pu.u[0] = pk2bf(p0, p1);
        pu.u[1] = pk2bf(p2, p3);
        O[qt][0] = __builtin_amdgcn_mfma_f32_16x16x16bf16_1k(pu.v, vlo, O[qt][0], 0, 0, 0);
        O[qt][1] = __builtin_amdgcn_mfma_f32_16x16x16bf16_1k(pu.v, vhi, O[qt][1], 0, 0, 0);
      }
    }
  }

  // ---- l reduction: sum over 4 g-groups; park per-wave in lL ----
#pragma unroll
  for (int qt = 0; qt < 4; ++qt) {
    float v = l_[qt];
    v += __shfl_xor(v, 16);
    v += __shfl_xor(v, 32);
    if (lane < 16) lL[w * 64 + qt * 16 + c16] = v;
  }

  // ---- epilogue: O/l * gate -> q slot (bf16) ----
#pragma unroll
  for (int qt = 0; qt < 4; ++qt)
#pragma unroll
    for (int i = 0; i < 4; ++i) {
      float l = lL[w * 64 + qt * 16 + g * 4 + i];
      float inv = 1.f / l;
      short* orow = rowbase + (size_t)(qb + qt * 16 + g * 4 + i) * LDQ16;
#pragma unroll
      for (int half = 0; half < 2; ++half) {
        int c = half * 16 + c16;
        float gv = bf2f(orow[768 + h * CH + c]);
        orow[h * CH + c] = f2bf(O[qt][half][i] * inv * gv);
      }
    }
}

// ---------------- output projection: out = oG @ Wo + bo, bf16 MFMA ----------------
__global__ __launch_bounds__(256) void out_proj(
    const short* __restrict__ og, const short* __restrict__ WoT,
    const float* __restrict__ bo, float* __restrict__ out)
{
  __shared__ short Al[64 * 136];
  __shared__ short Bl[128 * 136];
  const int tid = threadIdx.x;
  const int lane = tid & 63, w = tid >> 6;
  const int g = lane >> 4, c16 = lane & 15;
  const int wr = w & 1, wc = w >> 1;
  const int row0 = blockIdx.x * 64;

  f32x4 acc[2][4];
#pragma unroll
  for (int rt = 0; rt < 2; ++rt)
#pragma unroll
    for (int ct = 0; ct < 4; ++ct) acc[rt][ct] = (f32x4){0.f, 0.f, 0.f, 0.f};

  for (int kk0 = 0; kk0 < 256; kk0 += 128) {
#pragma unroll
    for (int ch = 0; ch < 4; ++ch) {
      int c = ch * 256 + tid;
      int r = c >> 4, kc = c & 15;
      *(bf16x8*)&Al[r * 136 + kc * 8] =
          *(const bf16x8*)(og + (size_t)(row0 + r) * LDQ16 + kk0 + kc * 8);
    }
#pragma unroll
    for (int ch = 0; ch < 8; ++ch) {
      int c = ch * 256 + tid;
      int r = c >> 4, kc = c & 15;
      *(bf16x8*)&Bl[r * 136 + kc * 8] =
          *(const bf16x8*)(WoT + (size_t)r * 256 + kk0 + kc * 8);
    }
    __syncthreads();
#pragma unroll
    for (int kk = 0; kk < 4; ++kk) {
      bf16x8 af[2], bfr[4];
#pragma unroll
      for (int rt = 0; rt < 2; ++rt)
        af[rt] = *(const bf16x8*)&Al[(wr * 32 + rt * 16 + c16) * 136 + kk * 32 + g * 8];
#pragma unroll
      for (int ct = 0; ct < 4; ++ct)
        bfr[ct] = *(const bf16x8*)&Bl[(wc * 64 + ct * 16 + c16) * 136 + kk * 32 + g * 8];
#pragma unroll
      for (int rt = 0; rt < 2; ++rt)
#pragma unroll
        for (int ct = 0; ct < 4; ++ct)
          acc[rt][ct] = __builtin_amdgcn_mfma_f32_16x16x32_bf16(af[rt], bfr[ct], acc[rt][ct], 0, 0, 0);
    }
    __syncthreads();
  }

#pragma unroll
  for (int rt = 0; rt < 2; ++rt)
#pragma unroll
    for (int ct = 0; ct < 4; ++ct) {
      int col = wc * 64 + ct * 16 + c16;
      float bv = bo[col];
#pragma unroll
      for (int i = 0; i < 4; ++i) {
        int row = row0 + wr * 32 + rt * 16 + g * 4 + i;
        out[(size_t)row * CIN + col] = acc[rt][ct][i] + bv;
      }
    }
}

extern "C" void kernel_launch(void* const* d_in, const int* in_sizes, int n_in,
                              void* d_out, int out_size, void* d_ws, size_t ws_size,
                              hipStream_t stream) {
  const float* x    = (const float*)d_in[0];
  const float* bias = (const float*)d_in[1];
  const void*  mask = d_in[2];
  const float* Wq   = (const float*)d_in[3];
  const float* Wk   = (const float*)d_in[4];
  const float* Wv   = (const float*)d_in[5];
  const float* Wo   = (const float*)d_in[6];
  const float* bo   = (const float*)d_in[7];
  const float* Wg   = (const float*)d_in[8];
  const float* bg   = (const float*)d_in[9];
  float* out = (float*)d_out;

  // ws: [flag 256B][WT 256KB][WoT 64KB][xb 16MB][qkvg bf16 128MB]
  unsigned int* flag = (unsigned int*)d_ws;
  short* WT   = (short*)((char*)d_ws + 256);
  short* WoT  = WT + 131072;
  short* xb   = WoT + 32768;
  short* qkvg = xb + (size_t)65536 * 128;

  prep<<<4161, 256, 0, stream>>>(x, Wq, Wk, Wv, Wg, Wo, (const uint4*)mask,
                                 xb, WT, WoT, flag);
  proj_qkvg<<<dim3(8, 512), 256, 0, stream>>>(xb, WT, bg, qkvg);
  attn<<<dim3(NH, 256), 256, 0, stream>>>(qkvg, bias, mask, flag);
  out_proj<<<1024, 256, 0, stream>>>(qkvg, WoT, bo, out);
}

// Round 7
// 245.694 us; speedup vs baseline: 1.0995x; 1.0858x over previous
//
#include <hip/hip_runtime.h>
#include <hip/hip_bf16.h>
#include <cstdint>

#define CIN 128
#define NH 8
#define CH 32

typedef short bf16x8 __attribute__((ext_vector_type(8)));
typedef short bf16x4 __attribute__((ext_vector_type(4)));
typedef float f32x4 __attribute__((ext_vector_type(4)));

__device__ __forceinline__ short f2bf(float f) {
  union { float f; unsigned u; } v; v.f = f;
  unsigned r = (v.u + 0x7FFFu + ((v.u >> 16) & 1u)) >> 16;   // RNE
  return (short)r;
}
__device__ __forceinline__ float bf2f(short s) {
  union { unsigned u; float f; } v; v.u = ((unsigned)(unsigned short)s) << 16;
  return v.f;
}
__device__ __forceinline__ unsigned pk2bf(float a, float b) {
  union { __hip_bfloat162 h; unsigned u; } cv;
  cv.h = __float22bfloat162_rn(make_float2(a, b));
  return cv.u;
}

// ---------------- prep: weights->bf16 [n][k] | mask detect ----------------
// blocks 0..63: WT/WoT ; 64: detect_mask
__global__ __launch_bounds__(256) void prep(
    const float* __restrict__ Wq, const float* __restrict__ Wk,
    const float* __restrict__ Wv, const float* __restrict__ Wg,
    const float* __restrict__ Wo,
    const uint4* __restrict__ mask,
    short* __restrict__ WT, short* __restrict__ WoT,
    unsigned int* __restrict__ flag)
{
  __shared__ int viol;
  const int b = blockIdx.x;
  if (b < 64) {
    const float qscale = 0.17677669529663689f;  // 1/sqrt(32)
#pragma unroll
    for (int e = 0; e < 10; ++e) {
      int o = b * 2560 + e * 256 + threadIdx.x;
      if (o < 131072) {
        int n = o >> 7, k = o & 127;
        int seg = n >> 8, nn = n & 255;
        const float* W = (seg == 0) ? Wq : (seg == 1) ? Wk : (seg == 2) ? Wv : Wg;
        float v = W[k * 256 + nn];
        if (seg == 0) v *= qscale;
        WT[o] = f2bf(v);
      } else {
        int o2 = o - 131072;
        int n = o2 >> 8, k = o2 & 255;
        WoT[o2] = f2bf(Wo[k * 128 + n]);
      }
    }
  } else {
    if (threadIdx.x == 0) viol = 0;
    __syncthreads();
    int v = 0;
#pragma unroll
    for (int j = 0; j < 16; ++j) {
      uint4 w = mask[j * 256 + threadIdx.x];
      v |= (w.x > 1u) | (w.y > 1u) | (w.z > 1u) | (w.w > 1u);
    }
    if (v) atomicOr(&viol, 1);
    __syncthreads();
    if (threadIdx.x == 0) *flag = viol ? 0u : 1u;
  }
}

// ---------------- fused QKVG-proj + flash attention, one block per srow ----------------
// 512 thr = 8 waves; each wave owns 32 q/key rows for projection and 32 q rows for attn.
// x-slice (256x128) staged bf16 in xl ONCE. Per head: K,V,Q,G projected by MFMA straight
// into the LDS layouts the R1-proven attention loop reads:
//   mfma(A,B) -> lane(g,c16) holds out[A-row = g*4+i][B-row = c16]   (v1 ground truth)
//   K,Q,G: mfma(Wf, xf) -> lane = 4 chans @ 1 key/q -> b64 write [row][chan] (pad 40)
//   V:     mfma(xf, Wf) -> lane = 4 keys  @ 1 chan -> b64 write [chan][key] (pad 264)
// Attention: R1 body (S^T = mfma(kf,qf); P stays in regs; PV = 2x 16x16x16), qt<2.
// Gated output -> og[65536][256] bf16. qkvg/xb never exist.
// LDS ~149 KB -> 1 block/CU; grid 256 = 1 block per CU, no tail. No min-waves bound.
__global__ __launch_bounds__(512) void fused_attn(
    const float* __restrict__ x, const short* __restrict__ WT,
    const float* __restrict__ bias, const float* __restrict__ bg,
    const void* __restrict__ maskraw, const unsigned int* __restrict__ flagp,
    short* __restrict__ og)
{
  __shared__ __align__(16) short xl[256 * 136];   // 69632 B
  __shared__ __align__(16) short kL[256 * 40];    // 20480 B [key][chan]
  __shared__ __align__(16) short vL[32 * 264];    // 16896 B [chan][key]
  __shared__ __align__(16) short qL[256 * 40];    // 20480 B [q][chan]
  __shared__ __align__(16) short gL[256 * 40];    // 20480 B [q][chan], sigmoid applied
  __shared__ float lL[256];
  __shared__ unsigned int scratch[8];

  const int tid = threadIdx.x;
  const int srow = blockIdx.x;
  const int lane = tid & 63, w = tid >> 6;
  const int g = lane >> 4, c16 = lane & 15;
  const int myrow = w * 32;

  // ---- mask row -> 8x u32 bits (waves 0..3) ----
  const unsigned int fl = *flagp;
  if (tid < 256) {
    int mv = fl ? ((const int*)maskraw)[srow * 256 + tid]
                : (int)((const unsigned char*)maskraw)[srow * 256 + tid];
    unsigned long long bb = __ballot(mv != 0);
    if (lane == 0) {
      scratch[w * 2 + 0] = (unsigned int)bb;
      scratch[w * 2 + 1] = (unsigned int)(bb >> 32);
    }
  }

  // ---- stage x-slice f32 -> bf16 xl[256][136] ----
  {
    const float* xs = x + (size_t)srow * 256 * 128;
#pragma unroll
    for (int it = 0; it < 16; ++it) {
      int idx = it * 512 + tid;          // float4 index
      int row = idx >> 5, c4 = idx & 31;
      float4 a = *(const float4*)(xs + (size_t)idx * 4);
      union { unsigned u[2]; bf16x4 v; } pu;
      pu.u[0] = pk2bf(a.x, a.y);
      pu.u[1] = pk2bf(a.z, a.w);
      *(bf16x4*)&xl[row * 136 + c4 * 4] = pu.v;
    }
  }
  __syncthreads();

  unsigned int mb[8];
#pragma unroll
  for (int j = 0; j < 8; ++j) mb[j] = scratch[j];

  const f32x4 zero4 = {0.f, 0.f, 0.f, 0.f};

#pragma unroll 1
  for (int h = 0; h < 8; ++h) {
    // ================= projection phase =================
    // K: mfma(Wf,xf): lane = K[chan ct*16+g*4+j][key myrow+rt*16+c16]
    {
      f32x4 acc[2][2];
#pragma unroll
      for (int ct = 0; ct < 2; ++ct)
#pragma unroll
        for (int rt = 0; rt < 2; ++rt) acc[ct][rt] = zero4;
#pragma unroll
      for (int kk = 0; kk < 4; ++kk) {
        bf16x8 wf[2], xf[2];
#pragma unroll
        for (int ct = 0; ct < 2; ++ct)
          wf[ct] = *(const bf16x8*)(WT + (size_t)(256 + h * CH + ct * 16 + c16) * 128 + kk * 32 + g * 8);
#pragma unroll
        for (int rt = 0; rt < 2; ++rt)
          xf[rt] = *(const bf16x8*)&xl[(myrow + rt * 16 + c16) * 136 + kk * 32 + g * 8];
#pragma unroll
        for (int ct = 0; ct < 2; ++ct)
#pragma unroll
          for (int rt = 0; rt < 2; ++rt)
            acc[ct][rt] = __builtin_amdgcn_mfma_f32_16x16x32_bf16(wf[ct], xf[rt], acc[ct][rt], 0, 0, 0);
      }
#pragma unroll
      for (int ct = 0; ct < 2; ++ct)
#pragma unroll
        for (int rt = 0; rt < 2; ++rt) {
          union { unsigned u[2]; bf16x4 v; } pu;
          pu.u[0] = pk2bf(acc[ct][rt][0], acc[ct][rt][1]);
          pu.u[1] = pk2bf(acc[ct][rt][2], acc[ct][rt][3]);
          *(bf16x4*)&kL[(myrow + rt * 16 + c16) * 40 + ct * 16 + g * 4] = pu.v;
        }
    }
    // V: mfma(xf,Wf): lane = V[key myrow+rt*16+g*4+j][chan ct*16+c16] -> vL[chan][key]
    {
      f32x4 acc[2][2];
#pragma unroll
      for (int rt = 0; rt < 2; ++rt)
#pragma unroll
        for (int ct = 0; ct < 2; ++ct) acc[rt][ct] = zero4;
#pragma unroll
      for (int kk = 0; kk < 4; ++kk) {
        bf16x8 wf[2], xf[2];
#pragma unroll
        for (int ct = 0; ct < 2; ++ct)
          wf[ct] = *(const bf16x8*)(WT + (size_t)(512 + h * CH + ct * 16 + c16) * 128 + kk * 32 + g * 8);
#pragma unroll
        for (int rt = 0; rt < 2; ++rt)
          xf[rt] = *(const bf16x8*)&xl[(myrow + rt * 16 + c16) * 136 + kk * 32 + g * 8];
#pragma unroll
        for (int rt = 0; rt < 2; ++rt)
#pragma unroll
          for (int ct = 0; ct < 2; ++ct)
            acc[rt][ct] = __builtin_amdgcn_mfma_f32_16x16x32_bf16(xf[rt], wf[ct], acc[rt][ct], 0, 0, 0);
      }
#pragma unroll
      for (int rt = 0; rt < 2; ++rt)
#pragma unroll
        for (int ct = 0; ct < 2; ++ct) {
          union { unsigned u[2]; bf16x4 v; } pu;
          pu.u[0] = pk2bf(acc[rt][ct][0], acc[rt][ct][1]);
          pu.u[1] = pk2bf(acc[rt][ct][2], acc[rt][ct][3]);
          *(bf16x4*)&vL[(ct * 16 + c16) * 264 + myrow + rt * 16 + g * 4] = pu.v;
        }
    }
    // Q: like K, seg 0 (scale pre-folded) -> qL[q][chan]
    {
      f32x4 acc[2][2];
#pragma unroll
      for (int ct = 0; ct < 2; ++ct)
#pragma unroll
        for (int rt = 0; rt < 2; ++rt) acc[ct][rt] = zero4;
#pragma unroll
      for (int kk = 0; kk < 4; ++kk) {
        bf16x8 wf[2], xf[2];
#pragma unroll
        for (int ct = 0; ct < 2; ++ct)
          wf[ct] = *(const bf16x8*)(WT + (size_t)(0 + h * CH + ct * 16 + c16) * 128 + kk * 32 + g * 8);
#pragma unroll
        for (int rt = 0; rt < 2; ++rt)
          xf[rt] = *(const bf16x8*)&xl[(myrow + rt * 16 + c16) * 136 + kk * 32 + g * 8];
#pragma unroll
        for (int ct = 0; ct < 2; ++ct)
#pragma unroll
          for (int rt = 0; rt < 2; ++rt)
            acc[ct][rt] = __builtin_amdgcn_mfma_f32_16x16x32_bf16(wf[ct], xf[rt], acc[ct][rt], 0, 0, 0);
      }
#pragma unroll
      for (int ct = 0; ct < 2; ++ct)
#pragma unroll
        for (int rt = 0; rt < 2; ++rt) {
          union { unsigned u[2]; bf16x4 v; } pu;
          pu.u[0] = pk2bf(acc[ct][rt][0], acc[ct][rt][1]);
          pu.u[1] = pk2bf(acc[ct][rt][2], acc[ct][rt][3]);
          *(bf16x4*)&qL[(myrow + rt * 16 + c16) * 40 + ct * 16 + g * 4] = pu.v;
        }
    }
    // G: like K, seg 3, sigmoid(v + bg) in f32 before store -> gL[q][chan]
    {
      f32x4 acc[2][2];
#pragma unroll
      for (int ct = 0; ct < 2; ++ct)
#pragma unroll
        for (int rt = 0; rt < 2; ++rt) acc[ct][rt] = zero4;
#pragma unroll
      for (int kk = 0; kk < 4; ++kk) {
        bf16x8 wf[2], xf[2];
#pragma unroll
        for (int ct = 0; ct < 2; ++ct)
          wf[ct] = *(const bf16x8*)(WT + (size_t)(768 + h * CH + ct * 16 + c16) * 128 + kk * 32 + g * 8);
#pragma unroll
        for (int rt = 0; rt < 2; ++rt)
          xf[rt] = *(const bf16x8*)&xl[(myrow + rt * 16 + c16) * 136 + kk * 32 + g * 8];
#pragma unroll
        for (int ct = 0; ct < 2; ++ct)
#pragma unroll
          for (int rt = 0; rt < 2; ++rt)
            acc[ct][rt] = __builtin_amdgcn_mfma_f32_16x16x32_bf16(wf[ct], xf[rt], acc[ct][rt], 0, 0, 0);
      }
#pragma unroll
      for (int ct = 0; ct < 2; ++ct) {
        float4 bgv = *(const float4*)(bg + h * CH + ct * 16 + g * 4);
#pragma unroll
        for (int rt = 0; rt < 2; ++rt) {
          float v0 = 1.f / (1.f + __expf(-(acc[ct][rt][0] + bgv.x)));
          float v1 = 1.f / (1.f + __expf(-(acc[ct][rt][1] + bgv.y)));
          float v2 = 1.f / (1.f + __expf(-(acc[ct][rt][2] + bgv.z)));
          float v3 = 1.f / (1.f + __expf(-(acc[ct][rt][3] + bgv.w)));
          union { unsigned u[2]; bf16x4 v; } pu;
          pu.u[0] = pk2bf(v0, v1);
          pu.u[1] = pk2bf(v2, v3);
          *(bf16x4*)&gL[(myrow + rt * 16 + c16) * 40 + ct * 16 + g * 4] = pu.v;
        }
      }
    }
    __syncthreads();   // K/V visible to all waves

    // ================= attention phase (R1 body, qt<2) =================
    const int qb = myrow;
    bf16x8 qf[2];
#pragma unroll
    for (int qt = 0; qt < 2; ++qt)
      qf[qt] = *(const bf16x8*)&qL[(qb + qt * 16 + c16) * 40 + g * 8];

    float l_[2] = {0.f, 0.f};
    f32x4 O[2][2];
#pragma unroll
    for (int qt = 0; qt < 2; ++qt) { O[qt][0] = zero4; O[qt][1] = zero4; }

    const float* bh = bias + (size_t)h * 65536;

#pragma unroll 1
    for (int ch = 0; ch < 8; ++ch) {
      float4 bb4[2][2];
#pragma unroll
      for (int kt = 0; kt < 2; ++kt)
#pragma unroll
        for (int qt = 0; qt < 2; ++qt)
          bb4[kt][qt] = *(const float4*)(bh + (size_t)(qb + qt * 16 + c16) * 256 +
                                         ch * 32 + kt * 16 + g * 4);

#pragma unroll
      for (int kt = 0; kt < 2; ++kt) {
        bf16x8 kf = *(const bf16x8*)&kL[(ch * 32 + kt * 16 + c16) * 40 + g * 8];
        bf16x4 vlo = *(const bf16x4*)&vL[(size_t)c16 * 264 + ch * 32 + kt * 16 + g * 4];
        bf16x4 vhi = *(const bf16x4*)&vL[(size_t)(16 + c16) * 264 + ch * 32 + kt * 16 + g * 4];
        const unsigned nib = (mb[ch] >> (kt * 16 + g * 4)) & 0xFu;
        float em[4];
#pragma unroll
        for (int i = 0; i < 4; ++i) em[i] = ((nib >> i) & 1u) ? 1.f : 0.f;
#pragma unroll
        for (int qt = 0; qt < 2; ++qt) {
          f32x4 S = __builtin_amdgcn_mfma_f32_16x16x32_bf16(kf, qf[qt], zero4, 0, 0, 0);
          float p0 = em[0] * __expf(fminf(S[0] + bb4[kt][qt].x, 85.f));
          float p1 = em[1] * __expf(fminf(S[1] + bb4[kt][qt].y, 85.f));
          float p2 = em[2] * __expf(fminf(S[2] + bb4[kt][qt].z, 85.f));
          float p3 = em[3] * __expf(fminf(S[3] + bb4[kt][qt].w, 85.f));
          l_[qt] += (p0 + p1) + (p2 + p3);
          union { unsigned u[2]; bf16x4 v; } pu;
          pu.u[0] = pk2bf(p0, p1);
          pu.u[1] = pk2bf(p2, p3);
          O[qt][0] = __builtin_amdgcn_mfma_f32_16x16x16bf16_1k(pu.v, vlo, O[qt][0], 0, 0, 0);
          O[qt][1] = __builtin_amdgcn_mfma_f32_16x16x16bf16_1k(pu.v, vhi, O[qt][1], 0, 0, 0);
        }
      }
    }

    // l reduction over 4 g-groups (wave-local)
#pragma unroll
    for (int qt = 0; qt < 2; ++qt) {
      float v = l_[qt];
      v += __shfl_xor(v, 16);
      v += __shfl_xor(v, 32);
      if (lane < 16) lL[myrow + qt * 16 + c16] = v;
    }

    // epilogue: O/l * gate -> og (wave-local reads of lL/gL)
#pragma unroll
    for (int qt = 0; qt < 2; ++qt)
#pragma unroll
      for (int i = 0; i < 4; ++i) {
        float l = lL[myrow + qt * 16 + g * 4 + i];
        float inv = 1.f / l;
        int row = qb + qt * 16 + g * 4 + i;
        short* orow = og + ((size_t)srow * 256 + row) * 256 + h * CH;
#pragma unroll
        for (int half = 0; half < 2; ++half) {
          int c = half * 16 + c16;
          float gv = bf2f(gL[row * 40 + c]);
          orow[c] = f2bf(O[qt][half][i] * inv * gv);
        }
      }
    __syncthreads();   // all attn reads of kL/vL done before next head overwrites
  }
}

// ---------------- output projection: out = og @ Wo + bo, bf16 MFMA ----------------
__global__ __launch_bounds__(256) void out_proj(
    const short* __restrict__ og, const short* __restrict__ WoT,
    const float* __restrict__ bo, float* __restrict__ out)
{
  __shared__ short Al[64 * 136];
  __shared__ short Bl[128 * 136];
  const int tid = threadIdx.x;
  const int lane = tid & 63, w = tid >> 6;
  const int g = lane >> 4, c16 = lane & 15;
  const int wr = w & 1, wc = w >> 1;
  const int row0 = blockIdx.x * 64;

  f32x4 acc[2][4];
#pragma unroll
  for (int rt = 0; rt < 2; ++rt)
#pragma unroll
    for (int ct = 0; ct < 4; ++ct) acc[rt][ct] = (f32x4){0.f, 0.f, 0.f, 0.f};

  for (int kk0 = 0; kk0 < 256; kk0 += 128) {
#pragma unroll
    for (int ch = 0; ch < 4; ++ch) {
      int c = ch * 256 + tid;
      int r = c >> 4, kc = c & 15;
      *(bf16x8*)&Al[r * 136 + kc * 8] =
          *(const bf16x8*)(og + (size_t)(row0 + r) * 256 + kk0 + kc * 8);
    }
#pragma unroll
    for (int ch = 0; ch < 8; ++ch) {
      int c = ch * 256 + tid;
      int r = c >> 4, kc = c & 15;
      *(bf16x8*)&Bl[r * 136 + kc * 8] =
          *(const bf16x8*)(WoT + (size_t)r * 256 + kk0 + kc * 8);
    }
    __syncthreads();
#pragma unroll
    for (int kk = 0; kk < 4; ++kk) {
      bf16x8 af[2], bfr[4];
#pragma unroll
      for (int rt = 0; rt < 2; ++rt)
        af[rt] = *(const bf16x8*)&Al[(wr * 32 + rt * 16 + c16) * 136 + kk * 32 + g * 8];
#pragma unroll
      for (int ct = 0; ct < 4; ++ct)
        bfr[ct] = *(const bf16x8*)&Bl[(wc * 64 + ct * 16 + c16) * 136 + kk * 32 + g * 8];
#pragma unroll
      for (int rt = 0; rt < 2; ++rt)
#pragma unroll
        for (int ct = 0; ct < 4; ++ct)
          acc[rt][ct] = __builtin_amdgcn_mfma_f32_16x16x32_bf16(af[rt], bfr[ct], acc[rt][ct], 0, 0, 0);
    }
    __syncthreads();
  }

#pragma unroll
  for (int rt = 0; rt < 2; ++rt)
#pragma unroll
    for (int ct = 0; ct < 4; ++ct) {
      int col = wc * 64 + ct * 16 + c16;
      float bv = bo[col];
#pragma unroll
      for (int i = 0; i < 4; ++i) {
        int row = row0 + wr * 32 + rt * 16 + g * 4 + i;
        out[(size_t)row * CIN + col] = acc[rt][ct][i] + bv;
      }
    }
}

extern "C" void kernel_launch(void* const* d_in, const int* in_sizes, int n_in,
                              void* d_out, int out_size, void* d_ws, size_t ws_size,
                              hipStream_t stream) {
  const float* x    = (const float*)d_in[0];
  const float* bias = (const float*)d_in[1];
  const void*  mask = d_in[2];
  const float* Wq   = (const float*)d_in[3];
  const float* Wk   = (const float*)d_in[4];
  const float* Wv   = (const float*)d_in[5];
  const float* Wo   = (const float*)d_in[6];
  const float* bo   = (const float*)d_in[7];
  const float* Wg   = (const float*)d_in[8];
  const float* bg   = (const float*)d_in[9];
  float* out = (float*)d_out;

  // ws: [flag 256B][WT 256KB][WoT 64KB][og bf16 33.5MB]
  unsigned int* flag = (unsigned int*)d_ws;
  short* WT  = (short*)((char*)d_ws + 256);
  short* WoT = WT + 131072;
  short* og  = WoT + 32768;

  prep<<<65, 256, 0, stream>>>(Wq, Wk, Wv, Wg, Wo, (const uint4*)mask,
                               WT, WoT, flag);
  fused_attn<<<256, 512, 0, stream>>>(x, WT, bias, bg, mask, flag, og);
  out_proj<<<1024, 256, 0, stream>>>(og, WoT, bo, out);
}